// Round 1
// 1678.034 us; speedup vs baseline: 1.1273x; 1.1273x over previous
//
#include <hip/hip_runtime.h>
#include <cstdint>

typedef unsigned short ushort_t;
typedef __bf16 bf16x8 __attribute__((ext_vector_type(8)));
typedef float f32x4 __attribute__((ext_vector_type(4)));

// ---- constants for this problem ----
// B=128, T=25, E=512, H=1024, V=32000, ENC=400
// K (padded input dim) = 1024 everywhere.
// Gate layout is ROW-PERMUTED everywhere: permuted row p = 4*unit + gate,
// original row = (p&3)*1024 + (p>>2)  (gate order i,f,g,o).
// This makes each 128-col tile of the gate GEMM own 32 complete units,
// so the LSTM cell fuses into the GEMM epilogue.

__device__ __forceinline__ ushort_t f2bf(float f) {
    unsigned u = __float_as_uint(f);
    unsigned r = (u + 0x7fffu + ((u >> 16) & 1u)) >> 16;
    return (ushort_t)r;
}

// ---------------- conversion / setup kernels ----------------

// float -> bf16, 4 elements per thread, n multiple of 4
__global__ void cvt4(const float* __restrict__ S, ushort_t* __restrict__ D, int n) {
    int i = (blockIdx.x * 256 + threadIdx.x) * 4;
    if (i >= n) return;
    float4 v = *(const float4*)(S + i);
    ushort4 o;
    o.x = f2bf(v.x); o.y = f2bf(v.y); o.z = f2bf(v.z); o.w = f2bf(v.w);
    *(ushort4*)(D + i) = o;
}

// W_ih [4096,912] -> bf16 padded [4096,1024], rows permuted to 4u+g order
__global__ void cvt_wih(const float* __restrict__ W, ushort_t* __restrict__ D) {
    int idx = blockIdx.x * 256 + threadIdx.x;   // 4096*1024
    int p = idx >> 10, col = idx & 1023;
    int orig = (p & 3) * 1024 + (p >> 2);
    D[idx] = (col < 912) ? f2bf(W[orig * 912 + col]) : (ushort_t)0;
}

// W_hh [4096,1024] -> bf16, rows permuted to 4u+g order
__global__ void cvt_whh(const float* __restrict__ W, ushort_t* __restrict__ D) {
    int idx = blockIdx.x * 256 + threadIdx.x;   // 4096*1024
    int p = idx >> 10, col = idx & 1023;
    int orig = (p & 3) * 1024 + (p >> 2);
    D[idx] = f2bf(W[orig * 1024 + col]);
}

// combined permuted bias: bc[p] = b_ih[orig] + b_hh[orig]
__global__ void bias_prep(const float* __restrict__ bi, const float* __restrict__ bh,
                          float* __restrict__ bc) {
    int p = blockIdx.x * 256 + threadIdx.x;     // 4096
    int orig = (p & 3) * 1024 + (p >> 2);
    bc[p] = bi[orig] + bh[orig];
}

// X_all bf16 [3200,1024]: row r = t*128+b; cols 0..511 word emb, 512..911 features, rest 0
__global__ void build_xall(const float* __restrict__ features, const int* __restrict__ captions,
                           const float* __restrict__ embW, ushort_t* __restrict__ X) {
    int idx = blockIdx.x * 256 + threadIdx.x;   // 3200*1024
    int r = idx >> 10, col = idx & 1023;
    int t = r >> 7, b = r & 127;
    float v;
    if (col < 512) {
        int tok = (t == 0) ? 1 : captions[b * 25 + (t - 1)];
        v = embW[tok * 512 + col];
    } else if (col < 912) {
        v = features[b * 400 + (col - 512)];
    } else {
        v = 0.f;
    }
    X[idx] = f2bf(v);
}

// ---------------- bf16 GEMM, C = A * B^T (+epilogue) ----------------
// A: [M,K] bf16 row-major, B: [N,K] bf16 row-major, K multiple of 64 (=1024 here).
// Tile 128x128, BK=64, 256 threads = 4 waves, each wave 64x64 via 4x4 mfma 16x16x32.
// mode 0: C[gm*ldc+gn] = acc
// mode 1: C[gm*ldc+gn] = acc + addsrc[gm*ldc+gn]
// mode 2: out[(gm&127)*24*32000 + (gm>>7)*32000 + gn] = acc + bias[gn]
//         with XCD-chunked block remap (grid must be 250x24):
//         XCD x owns bm in {3x,3x+1,3x+2}, sweeps bn with the 3 bm adjacent
//         -> per-XCD A working set 768 KB (L2-resident), B streamed once per XCD.
// mode 3: C[gm*ldc+gn] = acc + bias[gn]
__global__ __launch_bounds__(256)
void gemm_bt(const ushort_t* __restrict__ A, const ushort_t* __restrict__ B,
             float* __restrict__ C, const float* __restrict__ addsrc,
             const float* __restrict__ bias, int K, int mode) {
    const int ldc  = gridDim.x * 128;
    int bm = blockIdx.y, bn = blockIdx.x;
    if (mode == 2) {
        // dispatch id (x-fastest); id&7 tracks the XCD round-robin assignment
        int id  = blockIdx.y * gridDim.x + blockIdx.x;   // 0..5999
        int xcd = id & 7;
        int qq  = id >> 3;                               // 0..749 within XCD
        bm = xcd * 3 + (qq % 3);                         // 0..23
        bn = qq / 3;                                     // 0..249
    }
    const int tid  = threadIdx.x;
    const int wave = tid >> 6, lane = tid & 63;

    __shared__ __align__(16) ushort_t As[128 * 64];
    __shared__ __align__(16) ushort_t Bs[128 * 64];

    const ushort_t* Ab = A + (size_t)bm * 128 * K;
    const ushort_t* Bb = B + (size_t)bn * 128 * K;

    f32x4 acc[4][4] = {};

    const int wm = (wave & 1) * 64;
    const int wn = (wave >> 1) * 64;

    for (int k0 = 0; k0 < K; k0 += 64) {
#pragma unroll
        for (int ro = 0; ro < 4; ++ro) {
            int L   = ro * 256 + tid;       // 0..1023 chunk index (16B chunks)
            int row = L >> 3;               // 0..127
            int cs  = (L & 7) ^ (row & 7);  // swizzled source chunk within row
            const ushort_t* ga = Ab + row * K + k0 + cs * 8;
            const ushort_t* gb = Bb + row * K + k0 + cs * 8;
            __builtin_amdgcn_global_load_lds(
                (const __attribute__((address_space(1))) void*)ga,
                (__attribute__((address_space(3))) void*)(As + L * 8), 16, 0, 0);
            __builtin_amdgcn_global_load_lds(
                (const __attribute__((address_space(1))) void*)gb,
                (__attribute__((address_space(3))) void*)(Bs + L * 8), 16, 0, 0);
        }
        __syncthreads();   // drains vmcnt(0) then barrier -> LDS ready

#pragma unroll
        for (int kk = 0; kk < 2; ++kk) {
            bf16x8 af[4], bfr[4];
#pragma unroll
            for (int mt = 0; mt < 4; ++mt) {
                int row = wm + mt * 16 + (lane & 15);
                int cc  = (kk * 4 + (lane >> 4)) ^ (row & 7);
                af[mt]  = *(const bf16x8*)(As + row * 64 + cc * 8);
            }
#pragma unroll
            for (int nt = 0; nt < 4; ++nt) {
                int row = wn + nt * 16 + (lane & 15);
                int cc  = (kk * 4 + (lane >> 4)) ^ (row & 7);
                bfr[nt] = *(const bf16x8*)(Bs + row * 64 + cc * 8);
            }
#pragma unroll
            for (int mt = 0; mt < 4; ++mt)
#pragma unroll
                for (int nt = 0; nt < 4; ++nt)
                    acc[mt][nt] = __builtin_amdgcn_mfma_f32_16x16x32_bf16(
                        af[mt], bfr[nt], acc[mt][nt], 0, 0, 0);
        }
        __syncthreads();   // protect LDS before next stage overwrites
    }

    // epilogue: C/D layout col=lane&15, row=(lane>>4)*4+reg (m89/m91-verified)
    const int r0 = (lane >> 4) * 4;
    const int cn = lane & 15;
#pragma unroll
    for (int mt = 0; mt < 4; ++mt) {
#pragma unroll
        for (int nt = 0; nt < 4; ++nt) {
#pragma unroll
            for (int r = 0; r < 4; ++r) {
                int m  = wm + mt * 16 + r0 + r;
                int n  = wn + nt * 16 + cn;
                int gm = bm * 128 + m;
                int gn = bn * 128 + n;
                float v = acc[mt][nt][r];
                if (mode == 0) {
                    C[(size_t)gm * ldc + gn] = v;
                } else if (mode == 1) {
                    C[(size_t)gm * ldc + gn] = v + addsrc[(size_t)gm * ldc + gn];
                } else if (mode == 3) {
                    C[(size_t)gm * ldc + gn] = v + bias[gn];
                } else {
                    // gm = (t-1)*128 + b -> out[b, t-1, gn]
                    C[(size_t)(gm & 127) * (24 * 32000) + (size_t)(gm >> 7) * 32000 + gn]
                        = v + bias[gn];
                }
            }
        }
    }
}

// ---------------- fused recurrent step: gates GEMM + LSTM cell ----------------
// grid = 32 blocks (bn = gate-col tile). gates = hin @ Whh^T + gin (gin has bias).
// Whh rows permuted 4u+g -> block bn owns units [bn*32, bn*32+32), all 4 gates.
// acc -> LDS tile -> cell -> writes c (f32, natural unit order) and hout (bf16).
__global__ __launch_bounds__(256)
void lstm_step(const ushort_t* __restrict__ hin, const ushort_t* __restrict__ Whh,
               const float* __restrict__ gin, float* __restrict__ c,
               ushort_t* __restrict__ hout) {
    const int bn   = blockIdx.x;        // 0..31
    const int tid  = threadIdx.x;
    const int wave = tid >> 6, lane = tid & 63;
    const int K = 1024;

    __shared__ __align__(16) ushort_t As[128 * 64];
    __shared__ __align__(16) ushort_t Bs[128 * 64];
    __shared__ __align__(16) float    gt[128 * 132];   // pad 132: aligned float4, few conflicts

    const ushort_t* Ab = hin;                            // [128,1024]
    const ushort_t* Bb = Whh + (size_t)bn * 128 * K;

    f32x4 acc[4][4] = {};
    const int wm = (wave & 1) * 64;
    const int wn = (wave >> 1) * 64;

    for (int k0 = 0; k0 < K; k0 += 64) {
#pragma unroll
        for (int ro = 0; ro < 4; ++ro) {
            int L   = ro * 256 + tid;
            int row = L >> 3;
            int cs  = (L & 7) ^ (row & 7);
            const ushort_t* ga = Ab + row * K + k0 + cs * 8;
            const ushort_t* gb = Bb + row * K + k0 + cs * 8;
            __builtin_amdgcn_global_load_lds(
                (const __attribute__((address_space(1))) void*)ga,
                (__attribute__((address_space(3))) void*)(As + L * 8), 16, 0, 0);
            __builtin_amdgcn_global_load_lds(
                (const __attribute__((address_space(1))) void*)gb,
                (__attribute__((address_space(3))) void*)(Bs + L * 8), 16, 0, 0);
        }
        __syncthreads();
#pragma unroll
        for (int kk = 0; kk < 2; ++kk) {
            bf16x8 af[4], bfr[4];
#pragma unroll
            for (int mt = 0; mt < 4; ++mt) {
                int row = wm + mt * 16 + (lane & 15);
                int cc  = (kk * 4 + (lane >> 4)) ^ (row & 7);
                af[mt]  = *(const bf16x8*)(As + row * 64 + cc * 8);
            }
#pragma unroll
            for (int nt = 0; nt < 4; ++nt) {
                int row = wn + nt * 16 + (lane & 15);
                int cc  = (kk * 4 + (lane >> 4)) ^ (row & 7);
                bfr[nt] = *(const bf16x8*)(Bs + row * 64 + cc * 8);
            }
#pragma unroll
            for (int mt = 0; mt < 4; ++mt)
#pragma unroll
                for (int nt = 0; nt < 4; ++nt)
                    acc[mt][nt] = __builtin_amdgcn_mfma_f32_16x16x32_bf16(
                        af[mt], bfr[nt], acc[mt][nt], 0, 0, 0);
        }
        __syncthreads();
    }

    // gates tile -> LDS (add gates_in, which already carries both biases)
    const int r0 = (lane >> 4) * 4;
    const int cn = lane & 15;
#pragma unroll
    for (int mt = 0; mt < 4; ++mt)
#pragma unroll
        for (int nt = 0; nt < 4; ++nt)
#pragma unroll
            for (int r = 0; r < 4; ++r) {
                int m = wm + mt * 16 + r0 + r;          // batch row 0..127
                int n = wn + nt * 16 + cn;              // local gate col 0..127
                gt[m * 132 + n] = acc[mt][nt][r] + gin[(size_t)m * 4096 + bn * 128 + n];
            }
    __syncthreads();

    // cell: thread owns unit q = tid&31, 16 batch rows
    const int q = tid & 31;
    const int u = bn * 32 + q;                           // natural unit index
    const int bbase = (tid >> 5) * 16;
#pragma unroll
    for (int i = 0; i < 16; ++i) {
        int b = bbase + i;
        float4 g4 = *(const float4*)(gt + b * 132 + q * 4);   // i,f,g,o
        float si = 1.f / (1.f + expf(-g4.x));
        float sf = 1.f / (1.f + expf(-g4.y));
        float so = 1.f / (1.f + expf(-g4.w));
        int ci = b * 1024 + u;
        float cnew = sf * c[ci] + si * tanhf(g4.z);
        float hnew = so * tanhf(cnew);
        c[ci] = cnew;
        hout[ci] = f2bf(hnew);
    }
}

// ---------------- launch ----------------

extern "C" void kernel_launch(void* const* d_in, const int* in_sizes, int n_in,
                              void* d_out, int out_size, void* d_ws, size_t ws_size,
                              hipStream_t stream) {
    const float* features = (const float*)d_in[0];
    const int*   captions = (const int*)d_in[1];
    const float* emb_W    = (const float*)d_in[2];
    const float* W_ih     = (const float*)d_in[3];
    const float* W_hh     = (const float*)d_in[4];
    const float* b_ih     = (const float*)d_in[5];
    const float* b_hh     = (const float*)d_in[6];
    // d_in[7..12]: attention weights — provably dead code (softmax over 1 pixel)
    const float* fcn_W    = (const float*)d_in[13];
    const float* fcn_b    = (const float*)d_in[14];
    float* out = (float*)d_out;

    char* p = (char*)d_ws;
    auto alloc = [&](size_t bytes) { void* r = p; p += bytes; return r; };
    ushort_t* Xall     = (ushort_t*)alloc((size_t)3200 * 1024 * 2);   // 6.55 MB
    ushort_t* Wihb     = (ushort_t*)alloc((size_t)4096 * 1024 * 2);   // 8.39 MB (permuted)
    ushort_t* Whhb     = (ushort_t*)alloc((size_t)4096 * 1024 * 2);   // 8.39 MB (permuted)
    ushort_t* Fcnb     = (ushort_t*)alloc((size_t)32000 * 1024 * 2);  // 65.5 MB
    float*    gates_in = (float*)alloc((size_t)3200 * 4096 * 4);      // 52.4 MB (permuted cols, bias baked)
    float*    bc       = (float*)alloc((size_t)4096 * 4);             // 16 KB
    ushort_t* Hall     = (ushort_t*)alloc((size_t)3072 * 1024 * 2);   // 6.29 MB (h_2..h_25)
    ushort_t* hzero    = (ushort_t*)alloc((size_t)128 * 1024 * 2);
    ushort_t* htmp     = (ushort_t*)alloc((size_t)128 * 1024 * 2);
    float*    cbuf     = (float*)alloc((size_t)128 * 1024 * 4);
    (void)ws_size; (void)n_in; (void)in_sizes; (void)out_size;

    // zero recurrent state (ws is poisoned 0xAA before every timed launch)
    hipMemsetAsync(hzero, 0, (size_t)128 * 1024 * 2, stream);
    hipMemsetAsync(cbuf,  0, (size_t)128 * 1024 * 4, stream);

    // weight conversions (gate-permuted) + X_all + combined bias
    build_xall<<<(3200 * 1024) / 256, 256, 0, stream>>>(features, captions, emb_W, Xall);
    cvt_wih<<<(4096 * 1024) / 256, 256, 0, stream>>>(W_ih, Wihb);
    cvt_whh<<<(4096 * 1024) / 256, 256, 0, stream>>>(W_hh, Whhb);
    cvt4<<<(32000 * 1024) / 1024, 256, 0, stream>>>(fcn_W, Fcnb, 32000 * 1024);
    bias_prep<<<16, 256, 0, stream>>>(b_ih, b_hh, bc);

    // gates_in[3200,4096] = X_all @ W_ih_pad^T + (b_ih+b_hh)   (permuted col order)
    gemm_bt<<<dim3(32, 25), 256, 0, stream>>>(Xall, Wihb, gates_in, nullptr, bc, 1024, 3);

    // sequential LSTM: 25 fused steps (h double-buffers through htmp / Hall slices)
    for (int t = 0; t < 25; ++t) {
        const ushort_t* hin = (t == 0) ? hzero
                            : (t == 1) ? htmp
                            : Hall + (size_t)(t - 2) * 131072;
        ushort_t* hout = (t == 0) ? htmp : Hall + (size_t)(t - 1) * 131072;
        lstm_step<<<32, 256, 0, stream>>>(hin, Whhb,
                                          gates_in + (size_t)t * 128 * 4096,
                                          cbuf, hout);
    }

    // out[b, t-1, :] = Hall @ fcn_W^T + fcn_b   (XCD-chunked remap inside, mode 2)
    gemm_bt<<<dim3(250, 24), 256, 0, stream>>>(Hall, Fcnb, out, nullptr, fcn_b, 1024, 2);
}